// Round 4
// baseline (684.213 us; speedup 1.0000x reference)
//
#include <hip/hip_runtime.h>
#include <hip/hip_bf16.h>

// Problem constants (reference: T,B,D,H = 1024,512,128,128)
#define T_STEPS 1024
#define BATCH   512
#define DIM     128
#define G3      384          // 3*H gate rows
#define NCHUNK  (T_STEPS/8)  // 128 chunks of 8 steps

typedef __attribute__((ext_vector_type(8))) short bf16x8;
typedef __attribute__((ext_vector_type(4))) float f32x4;

#define LOG2E  1.44269504f   // r,z gate rows pre-scaled by log2(e)
#define LOG2E2 2.88539008f   // n gate rows pre-scaled by 2*log2(e)

// hbuf row stride in shorts: 128 cols + 32 pad -> chain stride 320B.
// Bank index of a fragment read = (16*ch + 4q + 16*kt) % 32: the 8 distinct
// 16B chunks (ch x q) land on 8 DISJOINT 4-bank groups (old 256B stride made
// the chain bit vanish mod 128B -> 2 addresses per bank group).
#define HSTRIDE 160

__device__ __forceinline__ short f2bf(float f) {
  unsigned u = __builtin_bit_cast(unsigned, f);
  u += 0x7FFFu + ((u >> 16) & 1u);   // round-to-nearest-even
  return (short)(u >> 16);
}

// LDS-only barrier: drains LDS ops for cross-wave visibility but does NOT
// drain vmcnt -> producer global prefetch stays in flight across steps.
__device__ __forceinline__ void block_sync_lds() {
  asm volatile("s_waitcnt lgkmcnt(0)\n\ts_barrier" ::: "memory");
}

// ---------------------------------------------------------------------------
// Prep: Wc = W_ih @ W1 (bf16), W_hh -> bf16, bc = W_ih @ b1 + b_ih (fp32).
// r/z rows scaled by log2e, n rows by 2*log2e -> gate math uses raw exp2.
// ---------------------------------------------------------------------------
__global__ void prep_kernel(const float* __restrict__ W1, const float* __restrict__ b1,
                            const float* __restrict__ W_ih, const float* __restrict__ W_hh,
                            const float* __restrict__ b_ih, const float* __restrict__ b_hh,
                            short* __restrict__ wc_bf, short* __restrict__ whh_bf,
                            float* __restrict__ bc, float* __restrict__ bhh_s) {
  const int g = blockIdx.x;
  const int d = threadIdx.x;
  const float sg = (g < 256) ? LOG2E : LOG2E2;
  float acc = 0.f;
  #pragma unroll 4
  for (int k = 0; k < 128; ++k)
    acc = fmaf(W_ih[g * 128 + k], W1[k * 128 + d], acc);
  wc_bf[g * 128 + d]  = f2bf(acc * sg);
  whh_bf[g * 128 + d] = f2bf(W_hh[g * 128 + d] * sg);

  __shared__ float red[128];
  red[d] = W_ih[g * 128 + d] * b1[d];
  __syncthreads();
  #pragma unroll
  for (int s = 64; s > 0; s >>= 1) {
    if (d < s) red[d] += red[d + s];
    __syncthreads();
  }
  if (d == 0) {
    bc[g]    = (red[0] + b_ih[g]) * sg;
    bhh_s[g] = b_hh[g] * sg;
  }
}

// ---------------------------------------------------------------------------
// Main GRU kernel. 256 blocks (2 chains) x 512 threads (8 waves, 2/SIMD).
// Waves 0-3 = CONSUMERS. Wave w owns h-cols [32w, 32w+32) = two 16-tiles x 3
// gates = 6 N-tiles = 24 MFMA/step (96/CU/step = the bf16 floor at C=2).
// DUPLICATE-ROW A-frag: A rows 0-7 carry h[chain0], rows 8-15 h[chain1]
// (lane reads hbuf[c>>3]). D reg0 of quads {0,1,2,3} holds {ch0,ch0,ch1,ch1}
// results, so quad parity selects the column half and EVERY lane does exactly
// one gate evaluation: lane(q,c): chain = q>>1, col = 32w + 16*(q&1) + c.
// All 24 MFMAs issue before any dependent VALU; sigmoids execute inside the
// final MFMA result-wait window. gi[s+1] is prefetched 1 step ahead (single
// b128/step, no chunk-start burst in front of the critical Ah reads).
// Waves 4-7 = PRODUCERS: gi for chunk c+1 during chunk c (M=16 = 8 steps x
// 2 chains), double-buffered gi4; MFMA work LEVELED at 2 (g,kt)-units/step
// over s=1..6 (was 6 MFMAs at s=1..4 -> barrier rounded every step up to the
// peak); x prefetched one chunk ahead; bias fold + publish at s==7.
// mfma_f32_16x16x32_bf16 layouts (m89-verified):
//   A[m=lane&15][k=quad*8+j], B[k=quad*8+j][n=lane&15], D: col=lane&15,row=quad*4+reg
// ---------------------------------------------------------------------------
__global__ __launch_bounds__(512, 2) void gru_kernel(
    const float* __restrict__ x,       // [T][B][D]
    const float* __restrict__ bhh_s,   // [384] scaled b_hh
    const short* __restrict__ wc_bf,   // [384][128] bf16 (scaled)
    const short* __restrict__ whh_bf,  // [384][128] bf16 (scaled)
    const float* __restrict__ bc,      // [384] (scaled)
    float* __restrict__ out)           // [B][H]
{
  const int tid = threadIdx.x;
  const int w   = tid >> 6;       // wave 0..7
  const int l   = tid & 63;
  const int q   = l >> 4;         // quad
  const int c   = l & 15;         // col-in-tile / A-row
  const int b0  = blockIdx.x * 2;

  __shared__ f32x4 gi4[2][16][128];        // [buf][m=2*step+chain][gatecol] (r,z,n,_) 64 KB
  __shared__ short hbuf[2][2][HSTRIDE];    // [parity][chain][col] bf16, 320B chain stride

  const f32x4 zero4 = {0.f, 0.f, 0.f, 0.f};

  if (w < 4) {
    // ================= CONSUMER =================
    const int half = q & 1;                    // 0 -> Tt0 cols, 1 -> Tt1 cols
    const int ch   = q >> 1;                   // this lane's chain
    const int colX = w * 32 + (half << 4) + c; // this lane's hidden col

    bf16x8 Bh[3][2][4];
    #pragma unroll
    for (int g = 0; g < 3; ++g)
      #pragma unroll
      for (int Tt = 0; Tt < 2; ++Tt)
        #pragma unroll
        for (int kt = 0; kt < 4; ++kt)
          Bh[g][Tt][kt] = *(const bf16x8*)(whh_bf +
              (g * 128 + w * 32 + Tt * 16 + c) * 128 + kt * 32 + q * 8);
    const float bhn = bhh_s[256 + colX];       // scaled by 2*log2e

    // zero parity-0 hbuf (320 shorts incl. pad) with the 256 consumer tids
    ((short*)hbuf)[tid] = 0;
    if (tid < 2 * HSTRIDE - 256) ((short*)hbuf)[256 + tid] = 0;
    float hp = 0.f;
    __syncthreads();

    // A-row c -> chain c>>3 (rows 0-7: chain0, 8-15: chain1), broadcast reads
    const short* hb0 = &hbuf[0][c >> 3][q * 8];
    const short* hb1 = &hbuf[1][c >> 3][q * 8];

    __builtin_amdgcn_s_setprio(1);
    for (int cc = 0; cc < NCHUNK; ++cc) {
      const f32x4* gp = &gi4[cc & 1][ch][colX];
      f32x4 gcur = gp[0];                 // gi for step 0 (m = 2*0 + ch)
      #pragma unroll
      for (int s = 0; s < 8; ++s) {
        const short* hb = (s & 1) ? hb1 : hb0;
        bf16x8 Ah[4];
        #pragma unroll
        for (int kt = 0; kt < 4; ++kt)
          Ah[kt] = *(const bf16x8*)(hb + kt * 32);
        f32x4 gnext = zero4;
        if (s < 7) gnext = gp[2 * (s + 1) * 128];   // 1-step-ahead gi prefetch

        // ---- all 24 MFMAs, split-K depth-2 chains per gate ----
        f32x4 r0A = __builtin_amdgcn_mfma_f32_16x16x32_bf16(Ah[0], Bh[0][0][0], zero4, 0, 0, 0);
        f32x4 r1A = __builtin_amdgcn_mfma_f32_16x16x32_bf16(Ah[0], Bh[0][1][0], zero4, 0, 0, 0);
        f32x4 r0B = __builtin_amdgcn_mfma_f32_16x16x32_bf16(Ah[2], Bh[0][0][2], zero4, 0, 0, 0);
        f32x4 r1B = __builtin_amdgcn_mfma_f32_16x16x32_bf16(Ah[2], Bh[0][1][2], zero4, 0, 0, 0);
        r0A = __builtin_amdgcn_mfma_f32_16x16x32_bf16(Ah[1], Bh[0][0][1], r0A, 0, 0, 0);
        r1A = __builtin_amdgcn_mfma_f32_16x16x32_bf16(Ah[1], Bh[0][1][1], r1A, 0, 0, 0);
        r0B = __builtin_amdgcn_mfma_f32_16x16x32_bf16(Ah[3], Bh[0][0][3], r0B, 0, 0, 0);
        r1B = __builtin_amdgcn_mfma_f32_16x16x32_bf16(Ah[3], Bh[0][1][3], r1B, 0, 0, 0);
        f32x4 z0A = __builtin_amdgcn_mfma_f32_16x16x32_bf16(Ah[0], Bh[1][0][0], zero4, 0, 0, 0);
        f32x4 z1A = __builtin_amdgcn_mfma_f32_16x16x32_bf16(Ah[0], Bh[1][1][0], zero4, 0, 0, 0);
        f32x4 z0B = __builtin_amdgcn_mfma_f32_16x16x32_bf16(Ah[2], Bh[1][0][2], zero4, 0, 0, 0);
        f32x4 z1B = __builtin_amdgcn_mfma_f32_16x16x32_bf16(Ah[2], Bh[1][1][2], zero4, 0, 0, 0);
        z0A = __builtin_amdgcn_mfma_f32_16x16x32_bf16(Ah[1], Bh[1][0][1], z0A, 0, 0, 0);
        z1A = __builtin_amdgcn_mfma_f32_16x16x32_bf16(Ah[1], Bh[1][1][1], z1A, 0, 0, 0);
        z0B = __builtin_amdgcn_mfma_f32_16x16x32_bf16(Ah[3], Bh[1][0][3], z0B, 0, 0, 0);
        z1B = __builtin_amdgcn_mfma_f32_16x16x32_bf16(Ah[3], Bh[1][1][3], z1B, 0, 0, 0);
        f32x4 n0A = __builtin_amdgcn_mfma_f32_16x16x32_bf16(Ah[0], Bh[2][0][0], zero4, 0, 0, 0);
        f32x4 n1A = __builtin_amdgcn_mfma_f32_16x16x32_bf16(Ah[0], Bh[2][1][0], zero4, 0, 0, 0);
        f32x4 n0B = __builtin_amdgcn_mfma_f32_16x16x32_bf16(Ah[2], Bh[2][0][2], zero4, 0, 0, 0);
        f32x4 n1B = __builtin_amdgcn_mfma_f32_16x16x32_bf16(Ah[2], Bh[2][1][2], zero4, 0, 0, 0);
        n0A = __builtin_amdgcn_mfma_f32_16x16x32_bf16(Ah[1], Bh[2][0][1], n0A, 0, 0, 0);
        n1A = __builtin_amdgcn_mfma_f32_16x16x32_bf16(Ah[1], Bh[2][1][1], n1A, 0, 0, 0);
        n0B = __builtin_amdgcn_mfma_f32_16x16x32_bf16(Ah[3], Bh[2][0][3], n0B, 0, 0, 0);
        n1B = __builtin_amdgcn_mfma_f32_16x16x32_bf16(Ah[3], Bh[2][1][3], n1B, 0, 0, 0);

        // ---- gate tail: sigmoids run inside the n-result wait window ----
        const float ghr = half ? (r1A[0] + r1B[0]) : (r0A[0] + r0B[0]);
        const float ghz = half ? (z1A[0] + z1B[0]) : (z0A[0] + z0B[0]);
        const float rg = __builtin_amdgcn_rcpf(1.f + __builtin_amdgcn_exp2f(-(gcur[0] + ghr)));
        const float zg = __builtin_amdgcn_rcpf(1.f + __builtin_amdgcn_exp2f(-(gcur[1] + ghz)));
        const float ghn = half ? (n1A[0] + n1B[0]) : (n0A[0] + n0B[0]);
        // n in 2*log2e units: tanh(nv) = 1 - 2/(exp2(nv_s)+1); no clamp needed:
        // exp2(+inf-ish)->inf, rcp(inf)=0 -> nn=1; exp2(-big)->0 -> nn=-1.
        const float nv = fmaf(rg, ghn + bhn, gcur[2]);
        const float e  = __builtin_amdgcn_exp2f(nv);
        const float nn = 1.f - 2.f * __builtin_amdgcn_rcpf(e + 1.f);
        const float h  = fmaf(zg, hp - nn, nn);
        hp = h;
        hbuf[(s & 1) ^ 1][ch][colX] = f2bf(h);
        gcur = gnext;
        block_sync_lds();
      }
    }
    __builtin_amdgcn_s_setprio(0);
    out[(size_t)(b0 + ch) * DIM + colX] = hp;
  } else {
    // ================= PRODUCER =================
    const int w4 = w - 4;
    const int jg0 = w4 * 32 + c, jg1 = jg0 + 16;
    bf16x8 Bc[3][2][4];
    #pragma unroll
    for (int g = 0; g < 3; ++g)
      #pragma unroll
      for (int Tt = 0; Tt < 2; ++Tt)
        #pragma unroll
        for (int kt = 0; kt < 4; ++kt)
          Bc[g][Tt][kt] = *(const bf16x8*)(wc_bf +
              (g * 128 + w4 * 32 + Tt * 16 + c) * 128 + kt * 32 + q * 8);
    const float fr0 = bc[jg0]       + bhh_s[jg0];
    const float fz0 = bc[128 + jg0] + bhh_s[128 + jg0];
    const float fn0 = bc[256 + jg0];
    const float fr1 = bc[jg1]       + bhh_s[jg1];
    const float fz1 = bc[128 + jg1] + bhh_s[128 + jg1];
    const float fn1 = bc[256 + jg1];

    const int trel = c >> 1, chn = c & 1;   // A-row m = c = 2*trel + chn
    f32x4 xv[8];

    // ---- pre-phase: build chunk 0 into buf 0, then prefetch chunk 1
    {
      const float* xb = x + ((size_t)trel * BATCH + (b0 + chn)) * DIM + q * 8;
      f32x4 xt[8];
      #pragma unroll
      for (int kt = 0; kt < 4; ++kt) {
        xt[2 * kt]     = *(const f32x4*)(xb + kt * 32);
        xt[2 * kt + 1] = *(const f32x4*)(xb + kt * 32 + 4);
      }
      bf16x8 Ax[4];
      #pragma unroll
      for (int kt = 0; kt < 4; ++kt) {
        const f32x4 v0 = xt[2 * kt], v1 = xt[2 * kt + 1];
        bf16x8 a;
        a[0] = f2bf(v0[0]); a[1] = f2bf(v0[1]); a[2] = f2bf(v0[2]); a[3] = f2bf(v0[3]);
        a[4] = f2bf(v1[0]); a[5] = f2bf(v1[1]); a[6] = f2bf(v1[2]); a[7] = f2bf(v1[3]);
        Ax[kt] = a;
      }
      f32x4 ga[2][3];
      #pragma unroll
      for (int g = 0; g < 3; ++g) {
        ga[0][g] = __builtin_amdgcn_mfma_f32_16x16x32_bf16(Ax[0], Bc[g][0][0], zero4, 0, 0, 0);
        ga[1][g] = __builtin_amdgcn_mfma_f32_16x16x32_bf16(Ax[0], Bc[g][1][0], zero4, 0, 0, 0);
      }
      #pragma unroll
      for (int kt = 1; kt < 4; ++kt)
        #pragma unroll
        for (int g = 0; g < 3; ++g) {
          ga[0][g] = __builtin_amdgcn_mfma_f32_16x16x32_bf16(Ax[kt], Bc[g][0][kt], ga[0][g], 0, 0, 0);
          ga[1][g] = __builtin_amdgcn_mfma_f32_16x16x32_bf16(Ax[kt], Bc[g][1][kt], ga[1][g], 0, 0, 0);
        }
      #pragma unroll
      for (int r = 0; r < 4; ++r) {
        f32x4 vA = {ga[0][0][r] + fr0, ga[0][1][r] + fz0, ga[0][2][r] + fn0, 0.f};
        f32x4 vB = {ga[1][0][r] + fr1, ga[1][1][r] + fz1, ga[1][2][r] + fn1, 0.f};
        gi4[0][4 * q + r][jg0] = vA;
        gi4[0][4 * q + r][jg1] = vB;
      }
      const float* xb1 = x + ((size_t)(8 + trel) * BATCH + (b0 + chn)) * DIM + q * 8;
      #pragma unroll
      for (int kt = 0; kt < 4; ++kt) {
        xv[2 * kt]     = *(const f32x4*)(xb1 + kt * 32);
        xv[2 * kt + 1] = *(const f32x4*)(xb1 + kt * 32 + 4);
      }
    }
    __syncthreads();

    for (int cc = 0; cc < NCHUNK; ++cc) {
      const int tc = cc + 1;            // chunk being produced
      bf16x8 Ax[4];
      f32x4 ga[2][3];
      #pragma unroll
      for (int s = 0; s < 8; ++s) {
        if (tc < NCHUNK) {
          if (s == 0) {
            #pragma unroll
            for (int kt = 0; kt < 4; ++kt) {
              const f32x4 v0 = xv[2 * kt], v1 = xv[2 * kt + 1];
              bf16x8 a;
              a[0] = f2bf(v0[0]); a[1] = f2bf(v0[1]); a[2] = f2bf(v0[2]); a[3] = f2bf(v0[3]);
              a[4] = f2bf(v1[0]); a[5] = f2bf(v1[1]); a[6] = f2bf(v1[2]); a[7] = f2bf(v1[3]);
              Ax[kt] = a;
            }
          } else if (s <= 6) {
            // LEVELED schedule: 2 (g,kt)-units = 4 MFMAs per step, s=1..6.
            // Unit u = 2*(s-1)+uu -> kt = u/3, g = u%3; kt==0 consumes zero C.
            #pragma unroll
            for (int uu = 0; uu < 2; ++uu) {
              const int u = 2 * (s - 1) + uu;
              const int kt = u / 3, g = u % 3;
              if (kt == 0) {
                ga[0][g] = __builtin_amdgcn_mfma_f32_16x16x32_bf16(Ax[0], Bc[g][0][0], zero4, 0, 0, 0);
                ga[1][g] = __builtin_amdgcn_mfma_f32_16x16x32_bf16(Ax[0], Bc[g][1][0], zero4, 0, 0, 0);
              } else {
                ga[0][g] = __builtin_amdgcn_mfma_f32_16x16x32_bf16(Ax[kt], Bc[g][0][kt], ga[0][g], 0, 0, 0);
                ga[1][g] = __builtin_amdgcn_mfma_f32_16x16x32_bf16(Ax[kt], Bc[g][1][kt], ga[1][g], 0, 0, 0);
              }
            }
            if (s == 5 && tc + 1 < NCHUNK) {  // prefetch x for chunk tc+1 (stays in flight)
              const float* xb = x + ((size_t)((tc + 1) * 8 + trel) * BATCH + (b0 + chn)) * DIM + q * 8;
              #pragma unroll
              for (int kt = 0; kt < 4; ++kt) {
                xv[2 * kt]     = *(const f32x4*)(xb + kt * 32);
                xv[2 * kt + 1] = *(const f32x4*)(xb + kt * 32 + 4);
              }
            }
          } else {  // s == 7: bias fold + publish gi for chunk tc
            const int nbuf = tc & 1;
            #pragma unroll
            for (int r = 0; r < 4; ++r) {
              f32x4 vA = {ga[0][0][r] + fr0, ga[0][1][r] + fz0, ga[0][2][r] + fn0, 0.f};
              f32x4 vB = {ga[1][0][r] + fr1, ga[1][1][r] + fz1, ga[1][2][r] + fn1, 0.f};
              gi4[nbuf][4 * q + r][jg0] = vA;
              gi4[nbuf][4 * q + r][jg1] = vB;
            }
          }
        }
        block_sync_lds();
      }
    }
  }
}

// ---------------------------------------------------------------------------
extern "C" void kernel_launch(void* const* d_in, const int* in_sizes, int n_in,
                              void* d_out, int out_size, void* d_ws, size_t ws_size,
                              hipStream_t stream) {
  const float* x    = (const float*)d_in[0];
  const float* W1   = (const float*)d_in[1];
  const float* b1   = (const float*)d_in[2];
  const float* W_ih = (const float*)d_in[3];
  const float* W_hh = (const float*)d_in[4];
  const float* b_ih = (const float*)d_in[5];
  const float* b_hh = (const float*)d_in[6];
  float* out = (float*)d_out;

  char* ws = (char*)d_ws;
  short* wc_bf  = (short*)(ws);             // 384*128 bf16
  short* whh_bf = (short*)(ws + 98304);     // 384*128 bf16
  float* bc     = (float*)(ws + 196608);    // 384 fp32
  float* bhh_s  = (float*)(ws + 198144);    // 384 fp32 (scaled b_hh)

  prep_kernel<<<dim3(G3), dim3(128), 0, stream>>>(W1, b1, W_ih, W_hh, b_ih, b_hh,
                                                  wc_bf, whh_bf, bc, bhh_s);
  gru_kernel<<<dim3(BATCH / 2), dim3(512), 0, stream>>>(x, bhh_s, wc_bf, whh_bf, bc, out);
}

// Round 5
// 682.224 us; speedup vs baseline: 1.0029x; 1.0029x over previous
//
#include <hip/hip_runtime.h>
#include <hip/hip_bf16.h>

// Problem constants (reference: T,B,D,H = 1024,512,128,128)
#define T_STEPS 1024
#define BATCH   512
#define DIM     128
#define G3      384          // 3*H gate rows
#define NCHUNK  (T_STEPS/8)  // 128 chunks of 8 steps

typedef __attribute__((ext_vector_type(8))) short bf16x8;
typedef __attribute__((ext_vector_type(4))) float f32x4;

#define LOG2E  1.44269504f   // r,z gate rows pre-scaled by log2(e)
#define LOG2E2 2.88539008f   // n gate rows pre-scaled by 2*log2(e)

// hbuf row stride in shorts: 128 cols + 32 pad -> chain stride 320B.
// Proven round 4: SQ_LDS_BANK_CONFLICT 16.8M -> 0.
#define HSTRIDE 160

__device__ __forceinline__ short f2bf(float f) {
  unsigned u = __builtin_bit_cast(unsigned, f);
  u += 0x7FFFu + ((u >> 16) & 1u);   // round-to-nearest-even
  return (short)(u >> 16);
}

// LDS-only barrier: drains LDS ops for cross-wave visibility but does NOT
// drain vmcnt -> producer global prefetch stays in flight across steps.
__device__ __forceinline__ void block_sync_lds() {
  asm volatile("s_waitcnt lgkmcnt(0)\n\ts_barrier" ::: "memory");
}

// ---------------------------------------------------------------------------
// Prep: Wc = W_ih @ W1 (bf16), W_hh -> bf16, bc = W_ih @ b1 + b_ih (fp32).
// r/z rows scaled by log2e, n rows by 2*log2e -> gate math uses raw exp2.
// ---------------------------------------------------------------------------
__global__ void prep_kernel(const float* __restrict__ W1, const float* __restrict__ b1,
                            const float* __restrict__ W_ih, const float* __restrict__ W_hh,
                            const float* __restrict__ b_ih, const float* __restrict__ b_hh,
                            short* __restrict__ wc_bf, short* __restrict__ whh_bf,
                            float* __restrict__ bc, float* __restrict__ bhh_s) {
  const int g = blockIdx.x;
  const int d = threadIdx.x;
  const float sg = (g < 256) ? LOG2E : LOG2E2;
  float acc = 0.f;
  #pragma unroll 4
  for (int k = 0; k < 128; ++k)
    acc = fmaf(W_ih[g * 128 + k], W1[k * 128 + d], acc);
  wc_bf[g * 128 + d]  = f2bf(acc * sg);
  whh_bf[g * 128 + d] = f2bf(W_hh[g * 128 + d] * sg);

  __shared__ float red[128];
  red[d] = W_ih[g * 128 + d] * b1[d];
  __syncthreads();
  #pragma unroll
  for (int s = 64; s > 0; s >>= 1) {
    if (d < s) red[d] += red[d + s];
    __syncthreads();
  }
  if (d == 0) {
    bc[g]    = (red[0] + b_ih[g]) * sg;
    bhh_s[g] = b_hh[g] * sg;
  }
}

// ---------------------------------------------------------------------------
// Main GRU kernel. 256 blocks (2 chains) x 512 threads (8 waves, 2/SIMD).
// Waves 0-3 = CONSUMERS (24 MFMA/step each); waves 4-7 = PRODUCERS (gi for
// chunk c+1, leveled 4 MFMA/step + 8 f2bf/step).
//
// STALL-FREE MFMA SCHEDULE (this round's change): a wave issues in order, so
// a dependent MFMA placed <L cycles after its producer stalls the wave AND
// everything behind it. Old order interleaved dependents 4 slots (~78cy)
// after producers -> 3 stall points/step if result latency L > 78. New order:
// all 12 INDEPENDENT MFMAs first (~233cy of issue, covers L<=~210), then the
// 12 dependents ordered r -> n -> z so results land in tail-consumption
// order (rg feeds the nv-fma first; zg is needed only at the final h-fma).
// mfma_f32_16x16x32_bf16 layouts (m89-verified):
//   A[m=lane&15][k=quad*8+j], B[k=quad*8+j][n=lane&15], D: col=lane&15,row=quad*4+reg
// ---------------------------------------------------------------------------
__global__ __launch_bounds__(512, 2) void gru_kernel(
    const float* __restrict__ x,       // [T][B][D]
    const float* __restrict__ bhh_s,   // [384] scaled b_hh
    const short* __restrict__ wc_bf,   // [384][128] bf16 (scaled)
    const short* __restrict__ whh_bf,  // [384][128] bf16 (scaled)
    const float* __restrict__ bc,      // [384] (scaled)
    float* __restrict__ out)           // [B][H]
{
  const int tid = threadIdx.x;
  const int w   = tid >> 6;       // wave 0..7
  const int l   = tid & 63;
  const int q   = l >> 4;         // quad
  const int c   = l & 15;         // col-in-tile / A-row
  const int b0  = blockIdx.x * 2;

  __shared__ f32x4 gi4[2][16][128];        // [buf][m=2*step+chain][gatecol] (r,z,n,_) 64 KB
  __shared__ short hbuf[2][2][HSTRIDE];    // [parity][chain][col] bf16, 320B chain stride

  const f32x4 zero4 = {0.f, 0.f, 0.f, 0.f};

  if (w < 4) {
    // ================= CONSUMER =================
    const int half = q & 1;                    // 0 -> Tt0 cols, 1 -> Tt1 cols
    const int ch   = q >> 1;                   // this lane's chain
    const int colX = w * 32 + (half << 4) + c; // this lane's hidden col

    bf16x8 Bh[3][2][4];
    #pragma unroll
    for (int g = 0; g < 3; ++g)
      #pragma unroll
      for (int Tt = 0; Tt < 2; ++Tt)
        #pragma unroll
        for (int kt = 0; kt < 4; ++kt)
          Bh[g][Tt][kt] = *(const bf16x8*)(whh_bf +
              (g * 128 + w * 32 + Tt * 16 + c) * 128 + kt * 32 + q * 8);
    const float bhn = bhh_s[256 + colX];       // scaled by 2*log2e

    // zero parity-0 hbuf (320 shorts incl. pad) with the 256 consumer tids
    ((short*)hbuf)[tid] = 0;
    if (tid < 2 * HSTRIDE - 256) ((short*)hbuf)[256 + tid] = 0;
    float hp = 0.f;
    __syncthreads();

    // A-row c -> chain c>>3 (rows 0-7: chain0, 8-15: chain1), broadcast reads
    const short* hb0 = &hbuf[0][c >> 3][q * 8];
    const short* hb1 = &hbuf[1][c >> 3][q * 8];

    __builtin_amdgcn_s_setprio(1);
    for (int cc = 0; cc < NCHUNK; ++cc) {
      const f32x4* gp = &gi4[cc & 1][ch][colX];
      f32x4 gcur = gp[0];                 // gi for step 0 (m = 2*0 + ch)
      #pragma unroll
      for (int s = 0; s < 8; ++s) {
        const short* hb = (s & 1) ? hb1 : hb0;
        bf16x8 Ah[4];
        #pragma unroll
        for (int kt = 0; kt < 4; ++kt)
          Ah[kt] = *(const bf16x8*)(hb + kt * 32);
        f32x4 gnext = zero4;
        if (s < 7) gnext = gp[2 * (s + 1) * 128];   // 1-step-ahead gi prefetch

        // ---- phase 1: 12 INDEPENDENT MFMAs (chain heads, kt0 & kt2) ----
        f32x4 r0A = __builtin_amdgcn_mfma_f32_16x16x32_bf16(Ah[0], Bh[0][0][0], zero4, 0, 0, 0);
        f32x4 r1A = __builtin_amdgcn_mfma_f32_16x16x32_bf16(Ah[0], Bh[0][1][0], zero4, 0, 0, 0);
        f32x4 r0B = __builtin_amdgcn_mfma_f32_16x16x32_bf16(Ah[2], Bh[0][0][2], zero4, 0, 0, 0);
        f32x4 r1B = __builtin_amdgcn_mfma_f32_16x16x32_bf16(Ah[2], Bh[0][1][2], zero4, 0, 0, 0);
        f32x4 n0A = __builtin_amdgcn_mfma_f32_16x16x32_bf16(Ah[0], Bh[2][0][0], zero4, 0, 0, 0);
        f32x4 n1A = __builtin_amdgcn_mfma_f32_16x16x32_bf16(Ah[0], Bh[2][1][0], zero4, 0, 0, 0);
        f32x4 n0B = __builtin_amdgcn_mfma_f32_16x16x32_bf16(Ah[2], Bh[2][0][2], zero4, 0, 0, 0);
        f32x4 n1B = __builtin_amdgcn_mfma_f32_16x16x32_bf16(Ah[2], Bh[2][1][2], zero4, 0, 0, 0);
        f32x4 z0A = __builtin_amdgcn_mfma_f32_16x16x32_bf16(Ah[0], Bh[1][0][0], zero4, 0, 0, 0);
        f32x4 z1A = __builtin_amdgcn_mfma_f32_16x16x32_bf16(Ah[0], Bh[1][1][0], zero4, 0, 0, 0);
        f32x4 z0B = __builtin_amdgcn_mfma_f32_16x16x32_bf16(Ah[2], Bh[1][0][2], zero4, 0, 0, 0);
        f32x4 z1B = __builtin_amdgcn_mfma_f32_16x16x32_bf16(Ah[2], Bh[1][1][2], zero4, 0, 0, 0);

        // ---- phase 2: 12 DEPENDENTS, ordered r -> n -> z ----
        r0A = __builtin_amdgcn_mfma_f32_16x16x32_bf16(Ah[1], Bh[0][0][1], r0A, 0, 0, 0);
        r1A = __builtin_amdgcn_mfma_f32_16x16x32_bf16(Ah[1], Bh[0][1][1], r1A, 0, 0, 0);
        r0B = __builtin_amdgcn_mfma_f32_16x16x32_bf16(Ah[3], Bh[0][0][3], r0B, 0, 0, 0);
        r1B = __builtin_amdgcn_mfma_f32_16x16x32_bf16(Ah[3], Bh[0][1][3], r1B, 0, 0, 0);
        n0A = __builtin_amdgcn_mfma_f32_16x16x32_bf16(Ah[1], Bh[2][0][1], n0A, 0, 0, 0);
        n1A = __builtin_amdgcn_mfma_f32_16x16x32_bf16(Ah[1], Bh[2][1][1], n1A, 0, 0, 0);
        n0B = __builtin_amdgcn_mfma_f32_16x16x32_bf16(Ah[3], Bh[2][0][3], n0B, 0, 0, 0);
        n1B = __builtin_amdgcn_mfma_f32_16x16x32_bf16(Ah[3], Bh[2][1][3], n1B, 0, 0, 0);
        z0A = __builtin_amdgcn_mfma_f32_16x16x32_bf16(Ah[1], Bh[1][0][1], z0A, 0, 0, 0);
        z1A = __builtin_amdgcn_mfma_f32_16x16x32_bf16(Ah[1], Bh[1][1][1], z1A, 0, 0, 0);
        z0B = __builtin_amdgcn_mfma_f32_16x16x32_bf16(Ah[3], Bh[1][0][3], z0B, 0, 0, 0);
        z1B = __builtin_amdgcn_mfma_f32_16x16x32_bf16(Ah[3], Bh[1][1][3], z1B, 0, 0, 0);

        // ---- gate tail: consumes results in arrival order r, n, z ----
        const float ghr = half ? (r1A[0] + r1B[0]) : (r0A[0] + r0B[0]);
        const float rg = __builtin_amdgcn_rcpf(1.f + __builtin_amdgcn_exp2f(-(gcur[0] + ghr)));
        const float ghn = half ? (n1A[0] + n1B[0]) : (n0A[0] + n0B[0]);
        // n in 2*log2e units: tanh(nv) = 1 - 2/(exp2(nv_s)+1); saturates clean.
        const float nv = fmaf(rg, ghn + bhn, gcur[2]);
        const float e  = __builtin_amdgcn_exp2f(nv);
        const float nn = 1.f - 2.f * __builtin_amdgcn_rcpf(e + 1.f);
        const float ghz = half ? (z1A[0] + z1B[0]) : (z0A[0] + z0B[0]);
        const float zg = __builtin_amdgcn_rcpf(1.f + __builtin_amdgcn_exp2f(-(gcur[1] + ghz)));
        const float h  = fmaf(zg, hp - nn, nn);
        hp = h;
        hbuf[(s & 1) ^ 1][ch][colX] = f2bf(h);
        gcur = gnext;
        block_sync_lds();
      }
    }
    __builtin_amdgcn_s_setprio(0);
    out[(size_t)(b0 + ch) * DIM + colX] = hp;
  } else {
    // ================= PRODUCER =================
    const int w4 = w - 4;
    const int jg0 = w4 * 32 + c, jg1 = jg0 + 16;
    bf16x8 Bc[3][2][4];
    #pragma unroll
    for (int g = 0; g < 3; ++g)
      #pragma unroll
      for (int Tt = 0; Tt < 2; ++Tt)
        #pragma unroll
        for (int kt = 0; kt < 4; ++kt)
          Bc[g][Tt][kt] = *(const bf16x8*)(wc_bf +
              (g * 128 + w4 * 32 + Tt * 16 + c) * 128 + kt * 32 + q * 8);
    const float fr0 = bc[jg0]       + bhh_s[jg0];
    const float fz0 = bc[128 + jg0] + bhh_s[128 + jg0];
    const float fn0 = bc[256 + jg0];
    const float fr1 = bc[jg1]       + bhh_s[jg1];
    const float fz1 = bc[128 + jg1] + bhh_s[128 + jg1];
    const float fn1 = bc[256 + jg1];

    const int trel = c >> 1, chn = c & 1;   // A-row m = c = 2*trel + chn
    f32x4 xv[8];

    // ---- pre-phase: build chunk 0 into buf 0, then prefetch chunk 1
    {
      const float* xb = x + ((size_t)trel * BATCH + (b0 + chn)) * DIM + q * 8;
      f32x4 xt[8];
      #pragma unroll
      for (int kt = 0; kt < 4; ++kt) {
        xt[2 * kt]     = *(const f32x4*)(xb + kt * 32);
        xt[2 * kt + 1] = *(const f32x4*)(xb + kt * 32 + 4);
      }
      bf16x8 Ax[4];
      #pragma unroll
      for (int kt = 0; kt < 4; ++kt) {
        const f32x4 v0 = xt[2 * kt], v1 = xt[2 * kt + 1];
        bf16x8 a;
        a[0] = f2bf(v0[0]); a[1] = f2bf(v0[1]); a[2] = f2bf(v0[2]); a[3] = f2bf(v0[3]);
        a[4] = f2bf(v1[0]); a[5] = f2bf(v1[1]); a[6] = f2bf(v1[2]); a[7] = f2bf(v1[3]);
        Ax[kt] = a;
      }
      f32x4 ga[2][3];
      #pragma unroll
      for (int g = 0; g < 3; ++g) {
        ga[0][g] = __builtin_amdgcn_mfma_f32_16x16x32_bf16(Ax[0], Bc[g][0][0], zero4, 0, 0, 0);
        ga[1][g] = __builtin_amdgcn_mfma_f32_16x16x32_bf16(Ax[0], Bc[g][1][0], zero4, 0, 0, 0);
      }
      #pragma unroll
      for (int kt = 1; kt < 4; ++kt)
        #pragma unroll
        for (int g = 0; g < 3; ++g) {
          ga[0][g] = __builtin_amdgcn_mfma_f32_16x16x32_bf16(Ax[kt], Bc[g][0][kt], ga[0][g], 0, 0, 0);
          ga[1][g] = __builtin_amdgcn_mfma_f32_16x16x32_bf16(Ax[kt], Bc[g][1][kt], ga[1][g], 0, 0, 0);
        }
      #pragma unroll
      for (int r = 0; r < 4; ++r) {
        f32x4 vA = {ga[0][0][r] + fr0, ga[0][1][r] + fz0, ga[0][2][r] + fn0, 0.f};
        f32x4 vB = {ga[1][0][r] + fr1, ga[1][1][r] + fz1, ga[1][2][r] + fn1, 0.f};
        gi4[0][4 * q + r][jg0] = vA;
        gi4[0][4 * q + r][jg1] = vB;
      }
      const float* xb1 = x + ((size_t)(8 + trel) * BATCH + (b0 + chn)) * DIM + q * 8;
      #pragma unroll
      for (int kt = 0; kt < 4; ++kt) {
        xv[2 * kt]     = *(const f32x4*)(xb1 + kt * 32);
        xv[2 * kt + 1] = *(const f32x4*)(xb1 + kt * 32 + 4);
      }
    }
    __syncthreads();

    for (int cc = 0; cc < NCHUNK; ++cc) {
      const int tc = cc + 1;            // chunk being produced
      bf16x8 Ax[4];
      f32x4 ga[2][3];
      #pragma unroll
      for (int s = 0; s < 8; ++s) {
        if (tc < NCHUNK) {
          // LEVELED f2bf: convert Ax[kt] one per step, just-in-time.
          // kt first used at s: kt0->1, kt1->2, kt2->4, kt3->5.
          if (s == 0 || s == 1 || s == 3 || s == 4) {
            const int ck = (s < 2) ? s : s - 1;       // 0,1,2,3
            const f32x4 v0 = xv[2 * ck], v1 = xv[2 * ck + 1];
            bf16x8 a;
            a[0] = f2bf(v0[0]); a[1] = f2bf(v0[1]); a[2] = f2bf(v0[2]); a[3] = f2bf(v0[3]);
            a[4] = f2bf(v1[0]); a[5] = f2bf(v1[1]); a[6] = f2bf(v1[2]); a[7] = f2bf(v1[3]);
            Ax[ck] = a;
          }
          if (s >= 1 && s <= 6) {
            // LEVELED MFMA schedule: 2 (g,kt)-units = 4 MFMAs per step, s=1..6.
            // Unit u = 2*(s-1)+uu -> kt = u/3, g = u%3; kt==0 consumes zero C.
            #pragma unroll
            for (int uu = 0; uu < 2; ++uu) {
              const int u = 2 * (s - 1) + uu;
              const int kt = u / 3, g = u % 3;
              if (kt == 0) {
                ga[0][g] = __builtin_amdgcn_mfma_f32_16x16x32_bf16(Ax[0], Bc[g][0][0], zero4, 0, 0, 0);
                ga[1][g] = __builtin_amdgcn_mfma_f32_16x16x32_bf16(Ax[0], Bc[g][1][0], zero4, 0, 0, 0);
              } else {
                ga[0][g] = __builtin_amdgcn_mfma_f32_16x16x32_bf16(Ax[kt], Bc[g][0][kt], ga[0][g], 0, 0, 0);
                ga[1][g] = __builtin_amdgcn_mfma_f32_16x16x32_bf16(Ax[kt], Bc[g][1][kt], ga[1][g], 0, 0, 0);
              }
            }
            if (s == 5 && tc + 1 < NCHUNK) {  // prefetch x for chunk tc+1 (stays in flight)
              const float* xb = x + ((size_t)((tc + 1) * 8 + trel) * BATCH + (b0 + chn)) * DIM + q * 8;
              #pragma unroll
              for (int kt = 0; kt < 4; ++kt) {
                xv[2 * kt]     = *(const f32x4*)(xb + kt * 32);
                xv[2 * kt + 1] = *(const f32x4*)(xb + kt * 32 + 4);
              }
            }
          } else if (s == 7) {  // bias fold + publish gi for chunk tc
            const int nbuf = tc & 1;
            #pragma unroll
            for (int r = 0; r < 4; ++r) {
              f32x4 vA = {ga[0][0][r] + fr0, ga[0][1][r] + fz0, ga[0][2][r] + fn0, 0.f};
              f32x4 vB = {ga[1][0][r] + fr1, ga[1][1][r] + fz1, ga[1][2][r] + fn1, 0.f};
              gi4[nbuf][4 * q + r][jg0] = vA;
              gi4[nbuf][4 * q + r][jg1] = vB;
            }
          }
        }
        block_sync_lds();
      }
    }
  }
}

// ---------------------------------------------------------------------------
extern "C" void kernel_launch(void* const* d_in, const int* in_sizes, int n_in,
                              void* d_out, int out_size, void* d_ws, size_t ws_size,
                              hipStream_t stream) {
  const float* x    = (const float*)d_in[0];
  const float* W1   = (const float*)d_in[1];
  const float* b1   = (const float*)d_in[2];
  const float* W_ih = (const float*)d_in[3];
  const float* W_hh = (const float*)d_in[4];
  const float* b_ih = (const float*)d_in[5];
  const float* b_hh = (const float*)d_in[6];
  float* out = (float*)d_out;

  char* ws = (char*)d_ws;
  short* wc_bf  = (short*)(ws);             // 384*128 bf16
  short* whh_bf = (short*)(ws + 98304);     // 384*128 bf16
  float* bc     = (float*)(ws + 196608);    // 384 fp32
  float* bhh_s  = (float*)(ws + 198144);    // 384 fp32 (scaled b_hh)

  prep_kernel<<<dim3(G3), dim3(128), 0, stream>>>(W1, b1, W_ih, W_hh, b_ih, b_hh,
                                                  wc_bf, whh_bf, bc, bhh_s);
  gru_kernel<<<dim3(BATCH / 2), dim3(512), 0, stream>>>(x, bhh_s, wc_bf, whh_bf, bc, out);
}